// Round 13
// baseline (143.669 us; speedup 1.0000x reference)
//
#include <hip/hip_runtime.h>
#include <cstddef>
#include <math.h>

#define NEXP    45
#define DIM     256
#define NTOK    4096
#define KH      128    // k's per block (half of DIM)
#define TBLK    16     // token slots per pass
#define DCH     64     // d's per LDS chunk
#define NCH     (DIM / DCH)
#define WROWQ   33     // W chunk row stride in quads (32 + 1 pad)
#define WROWF   (WROWQ * 4)
#define XROW    18     // x chunk row stride in floats (16 + 2 pad)
#define LISTCAP 64     // per-block m ~ Binom(4096,1/360): 11.4 +- 3.4; 64 > 15 sigma

// Zero d_out (harness re-poisons to 0xAA before every timed launch).
__global__ void pos_zero_kernel(float* out) { out[threadIdx.x] = 0.0f; }

// R13 = R11 resubmitted unchanged (R11/R12 never ran: GPU timeouts; two
// clean static audits). R10's nondeterministic-partition bug is fixed by
// partitioning on TOKEN ID: block th compacts only tokens with (n&7)==th —
// a deterministic set; in-block list order is irrelevant under max.
// Structure (from R4/R5/R8/R9 post-mortems): per-lane 4k x 2t outer product,
// per d-step 1 ds_read_b128 (W quad, K-major) + 1 ds_read_b64 (x pair,
// K-major) feed 8 v_fmac -> 0.25 LDS-reads/FMA, zero VMEM in the inner loop,
// both operand streams on the in-order lgkmcnt counter only.
__global__ __launch_bounds__(256, 4)
void pos_expert_kernel(const float* __restrict__ x, const int* __restrict__ tags,
                       const float* __restrict__ W, const float* __restrict__ bias,
                       float* __restrict__ out) {
  __shared__ alignas(16) float WT[DCH * WROWF];  // [d][132]: WT[d*132+k]=W[e][kh+k][ch*64+d], 33 KB
  __shared__ float xT[DCH * XROW];               // [d][18]:  xT[d*18+s]=x[tok(s)][ch*64+d], 4.6 KB
  __shared__ int   list[LISTCAP];
  __shared__ int   cnt;

  const int tid  = threadIdx.x;
  const int lane = tid & 63;
  const int wv   = tid >> 6;      // 4 waves: k-quads [wv*8, wv*8+8)
  const int tg   = lane >> 3;     // token-group 0..7 (2 slots each)
  const int kg   = lane & 7;      // k-group 0..7 (1 quad each)

  // XCD clustering: 720 = 8*90; same-expert blocks land on one XCD (L2 reuse).
  const int idx = (blockIdx.x & 7) * 90 + (blockIdx.x >> 3);
  const int e   = idx >> 4;
  const int sub = idx & 15;
  const int kh  = (sub >> 3) * KH;   // 0 or 128
  const int th  = sub & 7;           // deterministic token-id residue class

  if (tid == 0) cnt = 0;
  __syncthreads();
  // ---- compact tokens with tags==e AND n%8==th (deterministic set; order
  // within the block irrelevant under max; mask keeps writes in-bounds)
  for (int n = tid; n < NTOK; n += 256)
    if (tags[n] == e && (n & 7) == th) list[atomicAdd(&cnt, 1) & (LISTCAP - 1)] = n;
  __syncthreads();
  const int m = cnt;   // this block's token count (~11.4 avg)

  float mx[4] = {-INFINITY, -INFINITY, -INFINITY, -INFINITY};

  for (int p0 = 0; p0 < m; p0 += TBLK) {   // passes of 16 token slots (usually 1)
    float acc[4][2] = {};
    for (int ch = 0; ch < NCH; ++ch) {
      // ---- stage W chunk transposed: thread (kl=tid&127, hf=tid>>7) reads
      // 8 float4 of its W row, scatters 32 scalars; within a wave kl is
      // consecutive -> consecutive banks (2 words/bank = wave64 floor).
      {
        const int kl = tid & 127, hf = tid >> 7;
        const float4* Wr = (const float4*)(W + ((size_t)e * DIM + kh + kl) * DIM
                                           + ch * DCH + hf * 32);
#pragma unroll
        for (int j = 0; j < 8; ++j) {
          const float4 v = Wr[j];
          const int d = hf * 32 + j * 4;
          WT[(d + 0) * WROWF + kl] = v.x;
          WT[(d + 1) * WROWF + kl] = v.y;
          WT[(d + 2) * WROWF + kl] = v.z;
          WT[(d + 3) * WROWF + kl] = v.w;
        }
      }
      // ---- stage x chunk transposed: thread (ts=tid&15, ds=tid>>4) reads one
      // float4 of slot ts's row, scatters 4 scalars (<=2 words/bank).
      {
        const int ts = tid & 15, ds = tid >> 4;
        const int i  = p0 + ts;
        const int pos = (i < m) ? i : 0;          // clamp: dup slot, masked below
        const int tok = (m > 0) ? list[pos] : 0;
        const float4 v = *(const float4*)(x + (size_t)tok * DIM + ch * DCH + ds * 4);
        const int d = ds * 4;
        xT[(d + 0) * XROW + ts] = v.x;
        xT[(d + 1) * XROW + ts] = v.y;
        xT[(d + 2) * XROW + ts] = v.z;
        xT[(d + 3) * XROW + ts] = v.w;
      }
      __syncthreads();

      // ---- 64 d-steps: 1 b128 (8 distinct quads/wave, bank-groups 4*kg all
      // distinct, 8-way tg-broadcast free) + 1 b64 (16 consecutive words,
      // 8-way kg-broadcast) + 8 fmac; imm offsets under unroll.
      const float* wb = WT + (wv * 8 + kg) * 4;
      const float* xb = xT + tg * 2;
#pragma unroll 8
      for (int d = 0; d < DCH; ++d) {
        const float4 w4 = *(const float4*)(wb + d * WROWF);
        const float2 x2 = *(const float2*)(xb + d * XROW);
        acc[0][0] += w4.x * x2.x;  acc[0][1] += w4.x * x2.y;
        acc[1][0] += w4.y * x2.x;  acc[1][1] += w4.y * x2.y;
        acc[2][0] += w4.z * x2.x;  acc[2][1] += w4.z * x2.y;
        acc[3][0] += w4.w * x2.x;  acc[3][1] += w4.w * x2.y;
      }
      __syncthreads();   // before next chunk overwrites tiles
    }
    // fold this pass's 2 slots into the running k-max (validity-masked)
    const int i0 = p0 + tg * 2;
    const bool v0 = i0 < m, v1 = (i0 + 1) < m;
#pragma unroll
    for (int i = 0; i < 4; ++i) {
      float a = v0 ? acc[i][0] : -INFINITY;
      if (v1) a = fmaxf(a, acc[i][1]);
      mx[i] = fmaxf(mx[i], a);
    }
  }

  // reduce over the 8 token-groups: XOR lane bits 3..5 (tg), preserving kg
#pragma unroll
  for (int i = 0; i < 4; ++i) {
    mx[i] = fmaxf(mx[i], __shfl_xor(mx[i], 8, 64));
    mx[i] = fmaxf(mx[i], __shfl_xor(mx[i], 16, 64));
    mx[i] = fmaxf(mx[i], __shfl_xor(mx[i], 32, 64));
  }
  if (tg == 0) {
#pragma unroll
    for (int i = 0; i < 4; ++i) {
      const int k = kh + wv * 32 + kg * 4 + i;
      // bias commutes past token-max; relu last. Empty block: -inf -> y=0 (no-op).
      const float y = fmaxf(mx[i] + bias[(size_t)e * DIM + k], 0.0f);
      atomicMax((int*)out + k, __float_as_int(y));   // >=0: int order monotone
    }
  }
}

extern "C" void kernel_launch(void* const* d_in, const int* in_sizes, int n_in,
                              void* d_out, int out_size, void* d_ws, size_t ws_size,
                              hipStream_t stream) {
  const float* x    = (const float*)d_in[0];
  const int*   tags = (const int*)d_in[1];
  const float* W    = (const float*)d_in[2];
  const float* b    = (const float*)d_in[3];
  float*       out  = (float*)d_out;

  pos_zero_kernel<<<1, 256, 0, stream>>>(out);
  pos_expert_kernel<<<NEXP * 16, 256, 0, stream>>>(x, tags, W, b, out);
}